// Round 1
// baseline (457.815 us; speedup 1.0000x reference)
//
#include <hip/hip_runtime.h>
#include <hip/hip_bf16.h>

typedef __attribute__((ext_vector_type(4)))  float    f32x4;
typedef __attribute__((ext_vector_type(16))) float    f32x16;
typedef __attribute__((ext_vector_type(8)))  _Float16 f16x8;

#define NB 2
#define NN 384
#define NO 4
#define NC 128
#define NK 64
#define MT 64     // m rows per workgroup
#define NMT 6     // 384/64
#define LDA 72    // A_lds row stride (halves): 64 + 8 pad
#define LDZ 72    // Z_lds row stride (halves)

// ---------------------------------------------------------------------------
// Stage 1: per (b,o,mtile,split):  y1_partial[m,c] = sum_{n in split} sum_k
//          KB[b,m,n,o,k] * x[b,n,o,c] * Ws[k,c]
// GEMM over (n,k) with B-operand Z[k,c]=x[n,c]*Ws[k,c] built per-n in LDS.
// ---------------------------------------------------------------------------
__global__ __launch_bounds__(256, 3)
void sepconv_stage1(const float* __restrict__ KB, const float* __restrict__ X,
                    const float* __restrict__ Ws, float* __restrict__ part,
                    int ns)
{
    __shared__ _Float16 Alds[MT * LDA];   //  9.2 KB
    __shared__ _Float16 Zlds[NC * LDZ];   // 18.4 KB

    const int t  = threadIdx.x;
    const int wg = blockIdx.x;
    const int b  = wg & 1;
    const int o  = (wg >> 1) & 3;
    const int mt = (wg >> 3) % NMT;
    const int split = wg / (8 * NMT);
    const int n0 = split * ns;

    // per-thread W_spatial slice (fixed for whole kernel): c = t>>1, khalf = t&1
    const int zc = t >> 1;
    const int kh = t & 1;
    float wreg[32];
#pragma unroll
    for (int j = 0; j < 32; ++j)
        wreg[j] = Ws[(kh * 32 + j) * NC + zc];

    // A staging assignment: row = t>>2 (64 rows), 16 contiguous k per thread
    const int ar  = t >> 2;
    const int ak0 = (t & 3) * 16;
    const int m   = mt * MT + ar;
    const int abase = (b * NN + m) * (NN * NO * NK) + o * NK + ak0;
    const int xbase = (b * NN) * (NO * NC) + o * NC + zc;

    // MFMA fragment pointers: wave -> (msub = w&1, csubs {w>>1, 2+(w>>1)})
    const int lane = t & 63;
    const int wv   = t >> 6;
    const int msub = wv & 1;
    const int cs0  = wv >> 1;
    const int cs1  = 2 + (wv >> 1);
    const int half = lane >> 5;
    const int l31  = lane & 31;
    const _Float16* afp  = &Alds[(msub * 32 + l31) * LDA + half * 8];
    const _Float16* bfp0 = &Zlds[(cs0  * 32 + l31) * LDZ + half * 8];
    const _Float16* bfp1 = &Zlds[(cs1  * 32 + l31) * LDZ + half * 8];

    f32x16 acc0, acc1;
#pragma unroll
    for (int r = 0; r < 16; ++r) { acc0[r] = 0.f; acc1[r] = 0.f; }

    // prologue: prefetch n0
    f32x4 acur[4];
    float xcur;
    {
        const float* ap = KB + abase + n0 * (NO * NK);
#pragma unroll
        for (int j = 0; j < 4; ++j) acur[j] = ((const f32x4*)ap)[j];
        xcur = X[xbase + n0 * (NO * NC)];
    }

    for (int i = 0; i < ns; ++i) {
        // prefetch n+1 (clamped on last iter; harmless re-read)
        const int np = n0 + ((i + 1 < ns) ? (i + 1) : i);
        f32x4 anext[4];
        {
            const float* ap = KB + abase + np * (NO * NK);
#pragma unroll
            for (int j = 0; j < 4; ++j) anext[j] = ((const f32x4*)ap)[j];
        }
        const float xnext = X[xbase + np * (NO * NC)];

        // Z tile (transposed): Zlds[c][k] = x[n,c] * Ws[k,c], 32 halves/thread
#pragma unroll
        for (int v = 0; v < 4; ++v) {
            f16x8 z;
#pragma unroll
            for (int j = 0; j < 8; ++j) z[j] = (_Float16)(xcur * wreg[v * 8 + j]);
            *(f16x8*)&Zlds[zc * LDZ + kh * 32 + v * 8] = z;
        }
        // A tile: cvt 16 fp32 -> f16, two 16B LDS stores
#pragma unroll
        for (int v = 0; v < 2; ++v) {
            f16x8 a;
#pragma unroll
            for (int j = 0; j < 8; ++j)
                a[j] = (_Float16)(acur[v * 2 + (j >> 2)][j & 3]);
            *(f16x8*)&Alds[ar * LDA + ak0 + v * 8] = a;
        }
        __syncthreads();

        // 8 MFMAs per wave per n: D[m,c] += A[m,k] * Z[k,c]
#pragma unroll
        for (int kc = 0; kc < 4; ++kc) {
            f16x8 af  = *(const f16x8*)(afp  + kc * 16);
            f16x8 bf0 = *(const f16x8*)(bfp0 + kc * 16);
            f16x8 bf1 = *(const f16x8*)(bfp1 + kc * 16);
            acc0 = __builtin_amdgcn_mfma_f32_32x32x16_f16(af, bf0, acc0, 0, 0, 0);
            acc1 = __builtin_amdgcn_mfma_f32_32x32x16_f16(af, bf1, acc1, 0, 0, 0);
        }
        __syncthreads();

#pragma unroll
        for (int j = 0; j < 4; ++j) acur[j] = anext[j];
        xcur = xnext;
    }

    // epilogue: write fp32 partials [split][b][o][m][c]
    float* pb = part + ((size_t)((split * NB + b) * NO + o)) * (NN * NC);
#pragma unroll
    for (int r = 0; r < 16; ++r) {
        const int ml = (r & 3) + 8 * (r >> 2) + 4 * half;   // C/D row map (m74/m101)
        const int mm = mt * MT + msub * 32 + ml;
        pb[mm * NC + cs0 * 32 + l31] = acc0[r];
        pb[mm * NC + cs1 * 32 + l31] = acc1[r];
    }
}

// ---------------------------------------------------------------------------
// Stage 2: reduce splits, apply fiber/rot mixing + bias.
// out[b,m,p,c] = bias[c] + sum_o (sum_s part[s,b,o,m,c]) * rot[p,o,c]
// rot[p,o,c] = sum_k fiber[p,o,k] * Wr[k,c]   (recomputed per block; tiny)
// ---------------------------------------------------------------------------
__global__ __launch_bounds__(256)
void sepconv_stage2(const float* __restrict__ part, const float* __restrict__ fiber,
                    const float* __restrict__ Wr, const float* __restrict__ bias,
                    float* __restrict__ out, int nsplit)
{
    const int bid = blockIdx.x;            // 0 .. B*N-1
    const int b = bid / NN;
    const int m = bid % NN;
    const int t = threadIdx.x;
    const int c = t & 127;
    const int g = t >> 7;                  // 0/1 -> p in {2g, 2g+1}

    float rot[8];
#pragma unroll
    for (int i = 0; i < 8; ++i) rot[i] = 0.f;
    for (int k = 0; k < NK; ++k) {
        const float w = Wr[k * NC + c];
#pragma unroll
        for (int q = 0; q < 2; ++q)
#pragma unroll
            for (int oo = 0; oo < 4; ++oo)
                rot[q * 4 + oo] += fiber[((2 * g + q) * NO + oo) * NK + k] * w;
    }

    float y1[4];
#pragma unroll
    for (int oo = 0; oo < 4; ++oo) {
        float s = 0.f;
        for (int sp = 0; sp < nsplit; ++sp)
            s += part[((size_t)((sp * NB + b) * NO + oo)) * (NN * NC) + m * NC + c];
        y1[oo] = s;
    }

    const float bv = bias[c];
#pragma unroll
    for (int q = 0; q < 2; ++q) {
        float v = bv;
#pragma unroll
        for (int oo = 0; oo < 4; ++oo) v += y1[oo] * rot[q * 4 + oo];
        out[((b * NN + m) * NO + (2 * g + q)) * NC + c] = v;
    }
}

extern "C" void kernel_launch(void* const* d_in, const int* in_sizes, int n_in,
                              void* d_out, int out_size, void* d_ws, size_t ws_size,
                              hipStream_t stream)
{
    const float* X    = (const float*)d_in[0];
    const float* KB   = (const float*)d_in[1];
    const float* FB   = (const float*)d_in[2];
    const float* Ws   = (const float*)d_in[3];
    const float* Wr   = (const float*)d_in[4];
    const float* bias = (const float*)d_in[5];
    float* out  = (float*)d_out;
    float* part = (float*)d_ws;

    // one partial plane = B*O*N*C fp32 = 1.57 MB; prefer 16 splits (25 MB ws)
    const size_t per = (size_t)NB * NO * NN * NC * sizeof(float);
    int nsplit = 16;
    while (nsplit > 1 && (size_t)nsplit * per > ws_size) nsplit >>= 1;
    const int ns = NN / nsplit;

    sepconv_stage1<<<dim3(8 * NMT * nsplit), dim3(256), 0, stream>>>(KB, X, Ws, part, ns);
    sepconv_stage2<<<dim3(NB * NN), dim3(256), 0, stream>>>(part, FB, Wr, bias, out, nsplit);
}